// Round 6
// baseline (118.073 us; speedup 1.0000x reference)
//
#include <hip/hip_runtime.h>
#include <stdint.h>

// AdaptiveSparsityLayer: LayerNorm (biased var, eps=1e-5) + top-K mask (K=409 of 4096)
// K1 skeleton (NT=256, 1 row active, separate hist pass, wave0-scan, t0-select, 5 barriers)
// + 8-row-per-block software pipeline: row r+1's x-load issues during row r's selection.
// Fast-path barriers are raw s_barrier + lgkmcnt(0) (NO vmcnt drain) so prefetch loads
// stay in flight across the selection phase. Rare fallbacks use plain __syncthreads.

constexpr int FEATURES = 4096;
constexpr int KSEL     = 409;          // max(1, int(4096*0.1))
constexpr int NT       = 256;
constexpr int VPT      = FEATURES / NT / 4;   // 4 float4 per thread
constexpr int EPT      = FEATURES / NT;       // 16 elements per thread
constexpr int RPB      = 8;                   // rows per block -> grid 2048
constexpr float EPSF   = 1e-5f;
constexpr int NBINS    = 256;
constexpr int CAND_CAP = 64;

typedef float f32x4 __attribute__((ext_vector_type(4)));

__device__ __forceinline__ uint32_t key_of(float f) {
    uint32_t u = __float_as_uint(f);
    return (u & 0x80000000u) ? ~u : (u | 0x80000000u);  // ascending-order bijection
}
__device__ __forceinline__ float val_of(uint32_t k) {
    uint32_t u = (k & 0x80000000u) ? (k ^ 0x80000000u) : ~k;
    return __uint_as_float(u);
}

// Raw workgroup barrier: LDS producer visibility (lgkmcnt) WITHOUT vmcnt(0) drain,
// so global prefetch loads / pending stores stay in flight across it.
__device__ __forceinline__ void bar() {
    asm volatile("s_waitcnt lgkmcnt(0)" ::: "memory");
    __builtin_amdgcn_s_barrier();
}

__global__ __launch_bounds__(NT)
void lnk_kernel(const float* __restrict__ x, const float* __restrict__ g,
                const float* __restrict__ b, float* __restrict__ out)
{
    __shared__ float    s_f[8];
    __shared__ int      s_i[4];
    __shared__ uint32_t s_hist[NBINS];
    __shared__ uint32_t s_cand[CAND_CAP];
    __shared__ uint32_t s_n;
    __shared__ uint32_t s_T;
    __shared__ int      s_remK, s_above, s_keyhi, s_flag, s_doCut, s_needed;

    const int t    = threadIdx.x;
    const int lane = t & 63;
    const int wave = t >> 6;
    const size_t row0 = (size_t)blockIdx.x * RPB;

    const f32x4* gr = reinterpret_cast<const f32x4*>(g);
    const f32x4* br = reinterpret_cast<const f32x4*>(b);

    f32x4 xv[VPT], xn_[VPT];
    {   // prologue: load first row
        const f32x4* xr = reinterpret_cast<const f32x4*>(x + row0 * FEATURES);
        #pragma unroll
        for (int j = 0; j < VPT; ++j) xv[j] = __builtin_nontemporal_load(&xr[j * NT + t]);
    }

    #pragma unroll 1
    for (int rr = 0; rr < RPB; ++rr) {
        // ---- moments (single-pass sum/sumsq) ----
        float sum = 0.f, sq = 0.f;
        #pragma unroll
        for (int j = 0; j < VPT; ++j) {
            sum += (xv[j].x + xv[j].y) + (xv[j].z + xv[j].w);
            sq  += (xv[j].x * xv[j].x + xv[j].y * xv[j].y)
                 + (xv[j].z * xv[j].z + xv[j].w * xv[j].w);
        }
        #pragma unroll
        for (int o = 32; o; o >>= 1) { sum += __shfl_xor(sum, o); sq += __shfl_xor(sq, o); }
        if (lane == 0) { s_f[wave] = sum; s_f[4 + wave] = sq; }
        s_hist[t] = 0u;                       // pre-B1: prev readers done before B3(prev)
        bar();                                                     // B1
        if (t == 0) { s_n = 0u; s_flag = 0; } // post-B1: prev readers arrived at B1
        const float mean = (s_f[0] + s_f[1] + s_f[2] + s_f[3]) * (1.0f / FEATURES);
        const float ex2  = (s_f[4] + s_f[5] + s_f[6] + s_f[7]) * (1.0f / FEATURES);
        const float var  = fmaxf(ex2 - mean * mean, 0.0f);
        const float rstd = rsqrtf(var + EPSF);

        // ---- normalize -> order keys (xn recoverable bit-exactly) ----
        uint32_t keys[EPT];
        #pragma unroll
        for (int j = 0; j < VPT; ++j) {
            const f32x4 gv = gr[j * NT + t], bv = br[j * NT + t];
            #pragma unroll
            for (int k = 0; k < 4; ++k)
                keys[4 * j + k] = key_of((xv[j][k] - mean) * rstd * gv[k] + bv[k]);
        }

        // ---- prefetch next row (in flight across the whole selection phase) ----
        if (rr + 1 < RPB) {
            const f32x4* xr2 = reinterpret_cast<const f32x4*>(x + (row0 + rr + 1) * FEATURES);
            #pragma unroll
            for (int j = 0; j < VPT; ++j) xn_[j] = __builtin_nontemporal_load(&xr2[j * NT + t]);
        }

        // ---- integer-bin histogram over f in [1,2): e==383, bin=(key>>15)&255 ----
        int chi = 0;                      // count of f >= 2.0
        #pragma unroll
        for (int i = 0; i < EPT; ++i) {
            const uint32_t e = keys[i] >> 23;
            if (e >= 384u) ++chi;
            else if (e == 383u) atomicAdd(&s_hist[(keys[i] >> 15) & 255u], 1u);
        }
        #pragma unroll
        for (int o = 32; o; o >>= 1) chi += __shfl_xor(chi, o);
        if (lane == 0) s_i[wave] = chi;
        bar();                                                     // B2

        // ---- wave0: shuffle suffix scan + crossing-bin detect ----
        if (wave == 0) {
            const int cntHi = s_i[0] + s_i[1] + s_i[2] + s_i[3];
            const int R = KSEL - cntHi;       // rank to find below 2.0
            const int v0 = (int)s_hist[4 * lane + 0];
            const int v1 = (int)s_hist[4 * lane + 1];
            const int v2 = (int)s_hist[4 * lane + 2];
            const int v3 = (int)s_hist[4 * lane + 3];
            const int s3 = v3, s2 = v2 + s3, s1 = v1 + s2, s0 = v0 + s1;
            int suf = s0;
            #pragma unroll
            for (int o = 1; o < 64; o <<= 1) {
                const int u = __shfl_down(suf, o);
                suf += (lane + o < 64) ? u : 0;
            }
            const int excl = suf - s0;        // windowed count in bins >= 4*(lane+1)
            if (R >= 1) {
                const int bb[5] = { s0 + excl, s1 + excl, s2 + excl, s3 + excl, excl };
                #pragma unroll
                for (int i = 0; i < 4; ++i) {
                    if (bb[i] >= R && R > bb[i + 1]) {   // exactly one (lane,i) block-wide
                        s_remK  = R - bb[i + 1];
                        s_above = cntHi + bb[i + 1];
                        s_keyhi = (int)((0xBF800000u >> 15) + (uint32_t)(4 * lane + i));
                    }
                }
                if (lane == 0 && suf < R) s_flag = 1;    // window miss (below 1.0)
            } else if (lane == 0) s_flag = 1;            // threshold >= 2.0
        }
        bar();                                                     // B3

        int flag = s_flag;
        uint32_t T = 0u;
        int doCut = 0, needed = 0;

        // ---- fast path: gather crossing-bin candidates (17-bit match), t0 select ----
        if (!flag) {
            const uint32_t keyhi = (uint32_t)s_keyhi;
            #pragma unroll
            for (int i = 0; i < EPT; ++i) {
                if ((keys[i] >> 15) == keyhi) {
                    const uint32_t p = atomicAdd(&s_n, 1u);
                    if (p < CAND_CAP) s_cand[p] = keys[i];
                }
            }
            bar();                                                 // B4
            if (t == 0) {
                const int n = (int)s_n;
                if (n > CAND_CAP) s_flag = 1;
                else {
                    const int remK = s_remK;
                    uint32_t Tl = 0u; int gtT = 0, eqT = 0;
                    for (int i2 = 0; i2 < n; ++i2) {
                        const uint32_t ki = s_cand[i2];
                        int gt = 0, eq = 0;
                        for (int j2 = 0; j2 < n; ++j2) {
                            gt += (s_cand[j2] > ki); eq += (s_cand[j2] == ki);
                        }
                        if (gt < remK && remK <= gt + eq) { Tl = ki; gtT = gt; eqT = eq; break; }
                    }
                    s_T = Tl;
                    const int nd = KSEL - (s_above + gtT);   // all ==T keys are in this bin
                    s_needed = nd;
                    s_doCut  = (nd < eqT);
                }
            }
            bar();                                                 // B5
            flag = s_flag;
            if (!flag) { T = s_T; doCut = s_doCut; needed = s_needed; }
        }

        // ---- exact fallback: 32-step bit bisection (rare; plain __syncthreads) ----
        if (flag) {
            T = 0u;
            for (int bit = 31; bit >= 0; --bit) {
                const uint32_t candT = T | (1u << bit);
                int c = 0;
                #pragma unroll
                for (int i = 0; i < EPT; ++i) c += (keys[i] >= candT);
                #pragma unroll
                for (int o = 32; o; o >>= 1) c += __shfl_xor(c, o);
                __syncthreads();
                if (lane == 0) s_i[wave] = c;
                __syncthreads();
                c = s_i[0] + s_i[1] + s_i[2] + s_i[3];
                if (c >= KSEL) T = candT;        // block-uniform
            }
            int cg = 0, ce = 0;
            #pragma unroll
            for (int i = 0; i < EPT; ++i) { cg += (keys[i] > T); ce += (keys[i] == T); }
            int pk = (cg << 13) | ce;            // each total < 2^13
            #pragma unroll
            for (int o = 32; o; o >>= 1) pk += __shfl_xor(pk, o);
            __syncthreads();
            if (lane == 0) s_i[wave] = pk;
            __syncthreads();
            const int tot2  = s_i[0] + s_i[1] + s_i[2] + s_i[3];
            const int cntGt = tot2 >> 13, cntEq = tot2 & 8191;
            needed = KSEL - cntGt;
            doCut = (needed < cntEq);
        }

        // ---- rare: ties straddle boundary -> lowest-index cutoff ----
        int cutoff = FEATURES;
        if (doCut) {                             // block-uniform
            int lo2 = 0, hi2 = FEATURES;
            for (int it = 0; it < 12; ++it) {
                const int mid = (lo2 + hi2) >> 1;
                int cc = 0;
                #pragma unroll
                for (int i = 0; i < EPT; ++i) {
                    const int idx = 4 * ((i >> 2) * NT + t) + (i & 3);
                    cc += (keys[i] == T && idx < mid);
                }
                #pragma unroll
                for (int o = 32; o; o >>= 1) cc += __shfl_xor(cc, o);
                __syncthreads();
                if (lane == 0) s_i[wave] = cc;
                __syncthreads();
                const int ccs = s_i[0] + s_i[1] + s_i[2] + s_i[3];
                if (ccs >= needed) hi2 = mid; else lo2 = mid;
            }
            cutoff = hi2;
        }

        // ---- store: sel ? xn : 0 (nontemporal); issued AFTER prefetch so the next
        // iteration's wait can be vmcnt(4) (stores outstanding), not vmcnt(0) ----
        f32x4* outr = reinterpret_cast<f32x4*>(out + (row0 + rr) * FEATURES);
        if (!doCut) {                            // common case: sel = key >= T
            #pragma unroll
            for (int j = 0; j < VPT; ++j) {
                f32x4 o4;
                #pragma unroll
                for (int k = 0; k < 4; ++k) {
                    const uint32_t key = keys[4 * j + k];
                    o4[k] = (key >= T) ? val_of(key) : 0.0f;
                }
                __builtin_nontemporal_store(o4, &outr[j * NT + t]);
            }
        } else {
            #pragma unroll
            for (int j = 0; j < VPT; ++j) {
                f32x4 o4;
                #pragma unroll
                for (int k = 0; k < 4; ++k) {
                    const uint32_t key = keys[4 * j + k];
                    const int idx = 4 * (j * NT + t) + k;
                    const bool sel = (key > T) || (key == T && idx < cutoff);
                    o4[k] = sel ? val_of(key) : 0.0f;
                }
                __builtin_nontemporal_store(o4, &outr[j * NT + t]);
            }
        }

        // ---- rotate prefetched row into place ----
        #pragma unroll
        for (int j = 0; j < VPT; ++j) xv[j] = xn_[j];
    }
}

extern "C" void kernel_launch(void* const* d_in, const int* in_sizes, int n_in,
                              void* d_out, int out_size, void* d_ws, size_t ws_size,
                              hipStream_t stream) {
    const float* x = (const float*)d_in[0];
    const float* g = (const float*)d_in[1];
    const float* b = (const float*)d_in[2];
    float* out = (float*)d_out;
    const int batch = in_sizes[0] / FEATURES;
    hipLaunchKernelGGL(lnk_kernel, dim3(batch / RPB), dim3(NT), 0, stream, x, g, b, out);
}

// Round 7
// 108.003 us; speedup vs baseline: 1.0932x; 1.0932x over previous
//
#include <hip/hip_runtime.h>
#include <stdint.h>

// AdaptiveSparsityLayer: LayerNorm (biased var, eps=1e-5) + top-K mask (K=409 of 4096)
// K1 skeleton (NT=256, separate hist pass, wave0-scan, t0-select, 5 barriers) + 8-row
// LDS double-buffer pipeline: next row staged via global_load_lds (zero VGPR cost, the
// R5 failure) while current row's selection runs. In-wave quarter layout -> buffer
// readiness via own-wave counted vmcnt(4), no extra barrier. Barriers are raw
// s_barrier + lgkmcnt(0) (no vmcnt drain) so prefetch stays in flight.

constexpr int FEATURES = 4096;
constexpr int KSEL     = 409;          // max(1, int(4096*0.1))
constexpr int NT       = 256;
constexpr int VPT      = 4;            // float4 per thread
constexpr int EPT      = 16;           // elements per thread
constexpr int RPB      = 8;            // rows per block -> grid 2048
constexpr float EPSF   = 1e-5f;
constexpr int NBINS    = 256;
constexpr int CAND_CAP = 64;

typedef float f32x4 __attribute__((ext_vector_type(4)));

__device__ __forceinline__ uint32_t key_of(float f) {
    uint32_t u = __float_as_uint(f);
    return (u & 0x80000000u) ? ~u : (u | 0x80000000u);  // ascending-order bijection
}
__device__ __forceinline__ float val_of(uint32_t k) {
    uint32_t u = (k & 0x80000000u) ? (k ^ 0x80000000u) : ~k;
    return __uint_as_float(u);
}

// Raw workgroup barrier: LDS producer visibility WITHOUT vmcnt(0) drain.
__device__ __forceinline__ void bar() {
    asm volatile("s_waitcnt lgkmcnt(0)" ::: "memory");
    __builtin_amdgcn_s_barrier();
}

// 16B global -> LDS direct (dest = wave-uniform base + lane*16).
__device__ __forceinline__ void gload16(const float* gsrc, float* ldst) {
    __builtin_amdgcn_global_load_lds(
        (const __attribute__((address_space(1))) void*)gsrc,
        (__attribute__((address_space(3))) void*)(void*)ldst, 16, 0, 0);
}

__global__ __launch_bounds__(NT)
void lnk_kernel(const float* __restrict__ x, const float* __restrict__ g,
                const float* __restrict__ b, float* __restrict__ out)
{
    __shared__ float    s_buf[2][FEATURES];   // 32 KB double buffer
    __shared__ float    s_f[8];
    __shared__ int      s_i[4];
    __shared__ uint32_t s_hist[NBINS];
    __shared__ uint32_t s_cand[CAND_CAP];
    __shared__ uint32_t s_n;
    __shared__ uint32_t s_T;
    __shared__ int      s_remK, s_above, s_keyhi, s_flag, s_doCut, s_needed;

    const int t      = threadIdx.x;
    const int lane   = t & 63;
    const int wave   = t >> 6;
    const int baseF4 = wave * 256 + lane;     // this thread's float4-index base
    const size_t row0 = (size_t)blockIdx.x * RPB;

    const f32x4* gr = reinterpret_cast<const f32x4*>(g);
    const f32x4* br = reinterpret_cast<const f32x4*>(b);

    // prologue: stage row 0 into buf0 (wave w loads its own quarter)
    {
        const float* src = x + row0 * FEATURES;
        #pragma unroll
        for (int j = 0; j < VPT; ++j)
            gload16(src + 4 * (baseF4 + j * 64), &s_buf[0][4 * (wave * 256 + j * 64)]);
    }

    #pragma unroll 1
    for (int rr = 0; rr < RPB; ++rr) {
        // ---- stage next row into the other buffer (in flight across selection) ----
        if (rr + 1 < RPB) {
            const float* src = x + (row0 + rr + 1) * FEATURES;
            #pragma unroll
            for (int j = 0; j < VPT; ++j)
                gload16(src + 4 * (baseF4 + j * 64),
                        &s_buf[(rr + 1) & 1][4 * (wave * 256 + j * 64)]);
        }
        // own-wave wait: in-order retirement + >=4 younger VMEM ops (the 4 stores of
        // iter rr-1) guarantee this row's staging retired at vmcnt(4). Iter 0 has no
        // older stores to count against -> vmcnt(0).
        if (rr == 0) { asm volatile("s_waitcnt vmcnt(0)" ::: "memory"); }
        else         { asm volatile("s_waitcnt vmcnt(4)" ::: "memory"); }
        __builtin_amdgcn_sched_barrier(0);

        // ---- read row from LDS (own-wave quarter only) ----
        const float* buf = s_buf[rr & 1];
        f32x4 xv[VPT];
        #pragma unroll
        for (int j = 0; j < VPT; ++j)
            xv[j] = *reinterpret_cast<const f32x4*>(&buf[4 * (baseF4 + j * 64)]);

        // ---- moments (single-pass sum/sumsq) ----
        float sum = 0.f, sq = 0.f;
        #pragma unroll
        for (int j = 0; j < VPT; ++j) {
            sum += (xv[j].x + xv[j].y) + (xv[j].z + xv[j].w);
            sq  += (xv[j].x * xv[j].x + xv[j].y * xv[j].y)
                 + (xv[j].z * xv[j].z + xv[j].w * xv[j].w);
        }
        #pragma unroll
        for (int o = 32; o; o >>= 1) { sum += __shfl_xor(sum, o); sq += __shfl_xor(sq, o); }
        if (lane == 0) { s_f[wave] = sum; s_f[4 + wave] = sq; }
        s_hist[t] = 0u;                       // pre-B1: prev readers done before B3(prev)
        bar();                                                     // B1
        if (t == 0) { s_n = 0u; s_flag = 0; } // post-B1: prev readers arrived at B1
        const float mean = (s_f[0] + s_f[1] + s_f[2] + s_f[3]) * (1.0f / FEATURES);
        const float ex2  = (s_f[4] + s_f[5] + s_f[6] + s_f[7]) * (1.0f / FEATURES);
        const float var  = fmaxf(ex2 - mean * mean, 0.0f);
        const float rstd = rsqrtf(var + EPSF);

        // ---- normalize -> order keys (xn recoverable bit-exactly) ----
        uint32_t keys[EPT];
        #pragma unroll
        for (int j = 0; j < VPT; ++j) {
            const f32x4 gv = gr[baseF4 + j * 64], bv = br[baseF4 + j * 64];
            #pragma unroll
            for (int k = 0; k < 4; ++k)
                keys[4 * j + k] = key_of((xv[j][k] - mean) * rstd * gv[k] + bv[k]);
        }

        // ---- integer-bin histogram over f in [1,2): e==383, bin=(key>>15)&255 ----
        int chi = 0;                      // count of f >= 2.0
        #pragma unroll
        for (int i = 0; i < EPT; ++i) {
            const uint32_t e = keys[i] >> 23;
            if (e >= 384u) ++chi;
            else if (e == 383u) atomicAdd(&s_hist[(keys[i] >> 15) & 255u], 1u);
        }
        #pragma unroll
        for (int o = 32; o; o >>= 1) chi += __shfl_xor(chi, o);
        if (lane == 0) s_i[wave] = chi;
        bar();                                                     // B2

        // ---- wave0: shuffle suffix scan + crossing-bin detect ----
        if (wave == 0) {
            const int cntHi = s_i[0] + s_i[1] + s_i[2] + s_i[3];
            const int R = KSEL - cntHi;       // rank to find below 2.0
            const int v0 = (int)s_hist[4 * lane + 0];
            const int v1 = (int)s_hist[4 * lane + 1];
            const int v2 = (int)s_hist[4 * lane + 2];
            const int v3 = (int)s_hist[4 * lane + 3];
            const int s3 = v3, s2 = v2 + s3, s1 = v1 + s2, s0 = v0 + s1;
            int suf = s0;
            #pragma unroll
            for (int o = 1; o < 64; o <<= 1) {
                const int u = __shfl_down(suf, o);
                suf += (lane + o < 64) ? u : 0;
            }
            const int excl = suf - s0;        // windowed count in bins >= 4*(lane+1)
            if (R >= 1) {
                const int bb[5] = { s0 + excl, s1 + excl, s2 + excl, s3 + excl, excl };
                #pragma unroll
                for (int i = 0; i < 4; ++i) {
                    if (bb[i] >= R && R > bb[i + 1]) {   // exactly one (lane,i) block-wide
                        s_remK  = R - bb[i + 1];
                        s_above = cntHi + bb[i + 1];
                        s_keyhi = (int)((0xBF800000u >> 15) + (uint32_t)(4 * lane + i));
                    }
                }
                if (lane == 0 && suf < R) s_flag = 1;    // window miss (below 1.0)
            } else if (lane == 0) s_flag = 1;            // threshold >= 2.0
        }
        bar();                                                     // B3

        int flag = s_flag;
        uint32_t T = 0u;
        int doCut = 0, needed = 0;

        // ---- fast path: gather crossing-bin candidates (17-bit match), t0 select ----
        if (!flag) {
            const uint32_t keyhi = (uint32_t)s_keyhi;
            #pragma unroll
            for (int i = 0; i < EPT; ++i) {
                if ((keys[i] >> 15) == keyhi) {
                    const uint32_t p = atomicAdd(&s_n, 1u);
                    if (p < CAND_CAP) s_cand[p] = keys[i];
                }
            }
            bar();                                                 // B4
            if (t == 0) {
                const int n = (int)s_n;
                if (n > CAND_CAP) s_flag = 1;
                else {
                    const int remK = s_remK;
                    uint32_t Tl = 0u; int gtT = 0, eqT = 0;
                    for (int i2 = 0; i2 < n; ++i2) {
                        const uint32_t ki = s_cand[i2];
                        int gt = 0, eq = 0;
                        for (int j2 = 0; j2 < n; ++j2) {
                            gt += (s_cand[j2] > ki); eq += (s_cand[j2] == ki);
                        }
                        if (gt < remK && remK <= gt + eq) { Tl = ki; gtT = gt; eqT = eq; break; }
                    }
                    s_T = Tl;
                    const int nd = KSEL - (s_above + gtT);   // all ==T keys are in this bin
                    s_needed = nd;
                    s_doCut  = (nd < eqT);
                }
            }
            bar();                                                 // B5
            flag = s_flag;
            if (!flag) { T = s_T; doCut = s_doCut; needed = s_needed; }
        }

        // ---- exact fallback: 32-step bit bisection (rare; plain __syncthreads) ----
        if (flag) {
            T = 0u;
            for (int bit = 31; bit >= 0; --bit) {
                const uint32_t candT = T | (1u << bit);
                int c = 0;
                #pragma unroll
                for (int i = 0; i < EPT; ++i) c += (keys[i] >= candT);
                #pragma unroll
                for (int o = 32; o; o >>= 1) c += __shfl_xor(c, o);
                __syncthreads();
                if (lane == 0) s_i[wave] = c;
                __syncthreads();
                c = s_i[0] + s_i[1] + s_i[2] + s_i[3];
                if (c >= KSEL) T = candT;        // block-uniform
            }
            int cg = 0, ce = 0;
            #pragma unroll
            for (int i = 0; i < EPT; ++i) { cg += (keys[i] > T); ce += (keys[i] == T); }
            int pk = (cg << 13) | ce;            // each total < 2^13
            #pragma unroll
            for (int o = 32; o; o >>= 1) pk += __shfl_xor(pk, o);
            __syncthreads();
            if (lane == 0) s_i[wave] = pk;
            __syncthreads();
            const int tot2  = s_i[0] + s_i[1] + s_i[2] + s_i[3];
            const int cntGt = tot2 >> 13, cntEq = tot2 & 8191;
            needed = KSEL - cntGt;
            doCut = (needed < cntEq);
        }

        // ---- rare: ties straddle boundary -> lowest-index cutoff ----
        int cutoff = FEATURES;
        if (doCut) {                             // block-uniform
            int lo2 = 0, hi2 = FEATURES;
            for (int it = 0; it < 12; ++it) {
                const int mid = (lo2 + hi2) >> 1;
                int cc = 0;
                #pragma unroll
                for (int i = 0; i < EPT; ++i) {
                    const int idx = 4 * (baseF4 + ((i >> 2) << 6)) + (i & 3);
                    cc += (keys[i] == T && idx < mid);
                }
                #pragma unroll
                for (int o = 32; o; o >>= 1) cc += __shfl_xor(cc, o);
                __syncthreads();
                if (lane == 0) s_i[wave] = cc;
                __syncthreads();
                const int ccs = s_i[0] + s_i[1] + s_i[2] + s_i[3];
                if (ccs >= needed) hi2 = mid; else lo2 = mid;
            }
            cutoff = hi2;
        }

        // ---- store: sel ? xn : 0 (nontemporal, 4 b128 stores = the vmcnt(4) tokens) ----
        f32x4* outr = reinterpret_cast<f32x4*>(out + (row0 + rr) * FEATURES);
        if (!doCut) {                            // common case: sel = key >= T
            #pragma unroll
            for (int j = 0; j < VPT; ++j) {
                f32x4 o4;
                #pragma unroll
                for (int k = 0; k < 4; ++k) {
                    const uint32_t key = keys[4 * j + k];
                    o4[k] = (key >= T) ? val_of(key) : 0.0f;
                }
                __builtin_nontemporal_store(o4, &outr[baseF4 + j * 64]);
            }
        } else {
            #pragma unroll
            for (int j = 0; j < VPT; ++j) {
                f32x4 o4;
                #pragma unroll
                for (int k = 0; k < 4; ++k) {
                    const uint32_t key = keys[4 * j + k];
                    const int idx = 4 * (baseF4 + j * 64) + k;
                    const bool sel = (key > T) || (key == T && idx < cutoff);
                    o4[k] = sel ? val_of(key) : 0.0f;
                }
                __builtin_nontemporal_store(o4, &outr[baseF4 + j * 64]);
            }
        }
    }
}

extern "C" void kernel_launch(void* const* d_in, const int* in_sizes, int n_in,
                              void* d_out, int out_size, void* d_ws, size_t ws_size,
                              hipStream_t stream) {
    const float* x = (const float*)d_in[0];
    const float* g = (const float*)d_in[1];
    const float* b = (const float*)d_in[2];
    float* out = (float*)d_out;
    const int batch = in_sizes[0] / FEATURES;
    hipLaunchKernelGGL(lnk_kernel, dim3(batch / RPB), dim3(NT), 0, stream, x, g, b, out);
}

// Round 8
// 100.853 us; speedup vs baseline: 1.1707x; 1.0709x over previous
//
#include <hip/hip_runtime.h>
#include <stdint.h>

// AdaptiveSparsityLayer: LayerNorm (biased var, eps=1e-5) + top-K mask (K=409 of 4096)
// Exact K1 skeleton (R1, 98.9us): NT=256, one row/block, row in registers, integer-bin
// histogram over f in [1,2), wave0 shuffle suffix-scan, t0 serial select, 5 fast-path
// barriers. Deltas vs K1: __launch_bounds__(256,8) (VGPR<=64 -> 8 blocks/CU for
// cross-block bubble overlap; R6 counters showed 60 VGPR with comparable live set)
// and a block-uniform split store path (strictly less work in the common case).

constexpr int FEATURES = 4096;
constexpr int KSEL     = 409;          // max(1, int(4096*0.1))
constexpr int NT       = 256;
constexpr int VPT      = FEATURES / NT / 4;   // 4 float4 per thread
constexpr int EPT      = FEATURES / NT;       // 16 elements per thread
constexpr float EPSF   = 1e-5f;
constexpr int NBINS    = 256;
constexpr int CAND_CAP = 64;

typedef float f32x4 __attribute__((ext_vector_type(4)));

__device__ __forceinline__ uint32_t key_of(float f) {
    uint32_t u = __float_as_uint(f);
    return (u & 0x80000000u) ? ~u : (u | 0x80000000u);  // ascending-order bijection
}
__device__ __forceinline__ float val_of(uint32_t k) {
    uint32_t u = (k & 0x80000000u) ? (k ^ 0x80000000u) : ~k;
    return __uint_as_float(u);
}

__global__ __launch_bounds__(NT, 8)
void lnk_kernel(const float* __restrict__ x, const float* __restrict__ g,
                const float* __restrict__ b, float* __restrict__ out)
{
    __shared__ float    s_f[8];
    __shared__ int      s_i[4];
    __shared__ uint32_t s_hist[NBINS];
    __shared__ uint32_t s_cand[CAND_CAP];
    __shared__ uint32_t s_n;
    __shared__ uint32_t s_T;
    __shared__ int      s_remK, s_above, s_keyhi, s_flag, s_doCut, s_needed;

    const int t    = threadIdx.x;
    const int lane = t & 63;
    const int wave = t >> 6;
    const int row  = blockIdx.x;

    s_hist[t] = 0u;
    if (t == 0) { s_n = 0u; s_flag = 0; s_doCut = 0; }

    const f32x4* xr = reinterpret_cast<const f32x4*>(x + (size_t)row * FEATURES);
    const f32x4* gr = reinterpret_cast<const f32x4*>(g);
    const f32x4* br = reinterpret_cast<const f32x4*>(b);

    // ---- load row + single-pass sum/sumsq ----
    f32x4 xv[VPT];
    float sum = 0.f, sq = 0.f;
    #pragma unroll
    for (int j = 0; j < VPT; ++j) {
        xv[j] = __builtin_nontemporal_load(&xr[j * NT + t]);
        sum += (xv[j].x + xv[j].y) + (xv[j].z + xv[j].w);
        sq  += (xv[j].x * xv[j].x + xv[j].y * xv[j].y)
             + (xv[j].z * xv[j].z + xv[j].w * xv[j].w);
    }
    #pragma unroll
    for (int o = 32; o; o >>= 1) { sum += __shfl_xor(sum, o); sq += __shfl_xor(sq, o); }
    if (lane == 0) { s_f[wave] = sum; s_f[4 + wave] = sq; }
    __syncthreads();                                               // B1
    const float mean = (s_f[0] + s_f[1] + s_f[2] + s_f[3]) * (1.0f / FEATURES);
    const float ex2  = (s_f[4] + s_f[5] + s_f[6] + s_f[7]) * (1.0f / FEATURES);
    const float var  = fmaxf(ex2 - mean * mean, 0.0f);
    const float rstd = rsqrtf(var + EPSF);

    // ---- normalize -> order keys (xn recoverable bit-exactly) ----
    uint32_t keys[EPT];
    #pragma unroll
    for (int j = 0; j < VPT; ++j) {
        const f32x4 gv = gr[j * NT + t], bv = br[j * NT + t];
        #pragma unroll
        for (int k = 0; k < 4; ++k)
            keys[4 * j + k] = key_of((xv[j][k] - mean) * rstd * gv[k] + bv[k]);
    }

    // ---- separate pass: integer-bin histogram over f in [1,2) ----
    int chi = 0;                      // count of f >= 2.0
    #pragma unroll
    for (int i = 0; i < EPT; ++i) {
        const uint32_t e = keys[i] >> 23;     // positives: 256+exp; negatives < 256
        if (e >= 384u) ++chi;
        else if (e == 383u) atomicAdd(&s_hist[(keys[i] >> 15) & 255u], 1u);
    }
    #pragma unroll
    for (int o = 32; o; o >>= 1) chi += __shfl_xor(chi, o);
    if (lane == 0) s_i[wave] = chi;
    __syncthreads();                                               // B2

    // ---- wave0: shuffle suffix scan + crossing-bin detect ----
    if (wave == 0) {
        const int cntHi = s_i[0] + s_i[1] + s_i[2] + s_i[3];
        const int R = KSEL - cntHi;           // rank to find below 2.0
        const int v0 = (int)s_hist[4 * lane + 0];
        const int v1 = (int)s_hist[4 * lane + 1];
        const int v2 = (int)s_hist[4 * lane + 2];
        const int v3 = (int)s_hist[4 * lane + 3];
        const int s3 = v3, s2 = v2 + s3, s1 = v1 + s2, s0 = v0 + s1;
        int suf = s0;
        #pragma unroll
        for (int o = 1; o < 64; o <<= 1) {
            const int u = __shfl_down(suf, o);
            suf += (lane + o < 64) ? u : 0;
        }
        const int excl = suf - s0;            // windowed count in bins >= 4*(lane+1)
        if (R >= 1) {
            const int bb[5] = { s0 + excl, s1 + excl, s2 + excl, s3 + excl, excl };
            #pragma unroll
            for (int i = 0; i < 4; ++i) {
                if (bb[i] >= R && R > bb[i + 1]) {     // exactly one (lane,i) block-wide
                    s_remK  = R - bb[i + 1];           // needed from crossing bin
                    s_above = cntHi + bb[i + 1];       // strictly above the bin
                    s_keyhi = (int)((0xBF800000u >> 15) + (uint32_t)(4 * lane + i));
                }
            }
            if (lane == 0 && suf < R) s_flag = 1;      // window miss (below 1.0)
        } else if (lane == 0) s_flag = 1;              // threshold >= 2.0
    }
    __syncthreads();                                               // B3

    int flag = s_flag;
    uint32_t T = 0u;
    int doCut = 0, needed = 0;

    // ---- fast path: gather crossing-bin candidates (17-bit match), t0 select ----
    if (!flag) {
        const uint32_t keyhi = (uint32_t)s_keyhi;
        #pragma unroll
        for (int i = 0; i < EPT; ++i) {
            if ((keys[i] >> 15) == keyhi) {
                const uint32_t p = atomicAdd(&s_n, 1u);
                if (p < CAND_CAP) s_cand[p] = keys[i];
            }
        }
        __syncthreads();                                           // B4
        if (t == 0) {
            const int n = (int)s_n;
            if (n > CAND_CAP) s_flag = 1;
            else {
                const int remK = s_remK;
                uint32_t Tl = 0u; int gtT = 0, eqT = 0;
                for (int i2 = 0; i2 < n; ++i2) {
                    const uint32_t ki = s_cand[i2];
                    int gt = 0, eq = 0;
                    for (int j2 = 0; j2 < n; ++j2) {
                        gt += (s_cand[j2] > ki); eq += (s_cand[j2] == ki);
                    }
                    if (gt < remK && remK <= gt + eq) { Tl = ki; gtT = gt; eqT = eq; break; }
                }
                s_T = Tl;
                const int nd = KSEL - (s_above + gtT);   // all ==T keys are in this bin
                s_needed = nd;
                s_doCut  = (nd < eqT);
            }
        }
        __syncthreads();                                           // B5
        flag = s_flag;
        if (!flag) { T = s_T; doCut = s_doCut; needed = s_needed; }
    }

    // ---- exact fallback: 32-step bit bisection (rare) ----
    if (flag) {
        T = 0u;
        for (int bit = 31; bit >= 0; --bit) {
            const uint32_t candT = T | (1u << bit);
            int c = 0;
            #pragma unroll
            for (int i = 0; i < EPT; ++i) c += (keys[i] >= candT);
            #pragma unroll
            for (int o = 32; o; o >>= 1) c += __shfl_xor(c, o);
            __syncthreads();
            if (lane == 0) s_i[wave] = c;
            __syncthreads();
            c = s_i[0] + s_i[1] + s_i[2] + s_i[3];
            if (c >= KSEL) T = candT;        // block-uniform
        }
        int cg = 0, ce = 0;
        #pragma unroll
        for (int i = 0; i < EPT; ++i) { cg += (keys[i] > T); ce += (keys[i] == T); }
        int pk = (cg << 13) | ce;            // each total < 2^13
        #pragma unroll
        for (int o = 32; o; o >>= 1) pk += __shfl_xor(pk, o);
        __syncthreads();
        if (lane == 0) s_i[wave] = pk;
        __syncthreads();
        const int tot2  = s_i[0] + s_i[1] + s_i[2] + s_i[3];
        const int cntGt = tot2 >> 13, cntEq = tot2 & 8191;
        needed = KSEL - cntGt;
        doCut = (needed < cntEq);
    }

    // ---- rare: ties straddle boundary -> lowest-index cutoff ----
    int cutoff = FEATURES;
    if (doCut) {                             // block-uniform
        int lo2 = 0, hi2 = FEATURES;
        for (int it = 0; it < 12; ++it) {
            const int mid = (lo2 + hi2) >> 1;
            int cc = 0;
            #pragma unroll
            for (int i = 0; i < EPT; ++i) {
                const int idx = 4 * ((i >> 2) * NT + t) + (i & 3);
                cc += (keys[i] == T && idx < mid);
            }
            #pragma unroll
            for (int o = 32; o; o >>= 1) cc += __shfl_xor(cc, o);
            __syncthreads();
            if (lane == 0) s_i[wave] = cc;
            __syncthreads();
            const int ccs = s_i[0] + s_i[1] + s_i[2] + s_i[3];
            if (ccs >= needed) hi2 = mid; else lo2 = mid;
        }
        cutoff = hi2;
    }

    // ---- write: sel ? xn : 0 (nontemporal); uniform-branch common path ----
    f32x4* outr = reinterpret_cast<f32x4*>(out + (size_t)row * FEATURES);
    if (!doCut) {                            // block-uniform common case: sel = key >= T
        #pragma unroll
        for (int j = 0; j < VPT; ++j) {
            f32x4 o4;
            #pragma unroll
            for (int k = 0; k < 4; ++k) {
                const uint32_t key = keys[4 * j + k];
                o4[k] = (key >= T) ? val_of(key) : 0.0f;
            }
            __builtin_nontemporal_store(o4, &outr[j * NT + t]);
        }
    } else {
        #pragma unroll
        for (int j = 0; j < VPT; ++j) {
            f32x4 o4;
            #pragma unroll
            for (int k = 0; k < 4; ++k) {
                const uint32_t key = keys[4 * j + k];
                const int idx = 4 * (j * NT + t) + k;
                const bool sel = (key > T) || (key == T && idx < cutoff);
                o4[k] = sel ? val_of(key) : 0.0f;
            }
            __builtin_nontemporal_store(o4, &outr[j * NT + t]);
        }
    }
}

extern "C" void kernel_launch(void* const* d_in, const int* in_sizes, int n_in,
                              void* d_out, int out_size, void* d_ws, size_t ws_size,
                              hipStream_t stream) {
    const float* x = (const float*)d_in[0];
    const float* g = (const float*)d_in[1];
    const float* b = (const float*)d_in[2];
    float* out = (float*)d_out;
    const int batch = in_sizes[0] / FEATURES;
    hipLaunchKernelGGL(lnk_kernel, dim3(batch), dim3(NT), 0, stream, x, g, b, out);
}